// Round 6
// baseline (22872.015 us; speedup 1.0000x reference)
//
#include <hip/hip_runtime.h>
#include <stdint.h>

typedef __attribute__((ext_vector_type(8))) short short8;
typedef __attribute__((ext_vector_type(4))) float float4v;
typedef __attribute__((ext_vector_type(2))) float float2v;

constexpr int T = 128;
constexpr int NB = 512;          // batch
constexpr int NCH = 32;          // row chains (16 rows each)
constexpr int ROWS = 16;         // rows per chain
constexpr int CBLK = 12;         // blocks per chain (feature-column parallelism)
// Padded hidden layout per row: h0 @0 (538->544), h1 @544 (358->384), h2 @928 (128)
constexpr int HS = 1056;

__device__ __forceinline__ float bf2f(ushort u) {
  union { float f; uint32_t i; } v; v.i = ((uint32_t)u) << 16; return v.f;
}
__device__ __forceinline__ ushort f2bf(float f) {
  union { float f; uint32_t i; } v; v.f = f;
  uint32_t i = v.i;
  uint32_t r = i + 0x7FFFu + ((i >> 16) & 1u);
  return (ushort)(r >> 16);
}

// Cross-block h state: AGENT scope (device coherence point; MALL-cacheable).
__device__ __forceinline__ unsigned long long coh_load8(const float* p) {
  return __hip_atomic_load(
      reinterpret_cast<unsigned long long*>(const_cast<float*>(p)),
      __ATOMIC_RELAXED, __HIP_MEMORY_SCOPE_AGENT);
}
__device__ __forceinline__ void coh_store8(float* p, float a, float b) {
  union { unsigned long long u; float f[2]; } v; v.f[0] = a; v.f[1] = b;
  __hip_atomic_store(reinterpret_cast<unsigned long long*>(p), v.u,
                     __ATOMIC_RELAXED, __HIP_MEMORY_SCOPE_AGENT);
}

// ---------------------------------------------------------------------------
// Pack f32 weights (optionally masked) into SPLIT bf16 MFMA B-fragment layout,
// with k-axis SEGMENT ROTATION: packed k index p maps to source column
//   p <  POLD : src = SOFF + p   (valid if p < OLDLEN, else zero)   [old-state]
//   p >= POLD : src = p - POLD   (valid if src < NEWLEN, else zero) [new-state]
// ---------------------------------------------------------------------------
__global__ __launch_bounds__(256) void pack_w(const float* __restrict__ W,
                                              const float* __restrict__ mask,
                                              ushort* __restrict__ out, int loOff,
                                              int NN, int IT, int NT, int KB,
                                              int POLD, int OLDLEN, int SOFF,
                                              int NEWLEN) {
  int idx = blockIdx.x * 256 + threadIdx.x;
  int total = KB * NT * 512;
  if (idx >= total) return;
  int jj   = idx & 7;
  int lane = (idx >> 3) & 63;
  int nt   = (idx >> 9) % NT;
  int kb   = (idx >> 9) / NT;
  int n = nt * 16 + (lane & 15);
  int p = kb * 32 + (lane >> 4) * 8 + jj;
  int src = -1;
  if (p < POLD) {
    if (p < OLDLEN) src = SOFF + p;
  } else {
    int q = p - POLD;
    if (q < NEWLEN) src = q;
  }
  float v = 0.f;
  if (n < NN && src >= 0) {
    v = W[(size_t)n * IT + src];
    if (mask) v *= mask[(size_t)n * IT + src];
  }
  ushort hi = f2bf(v);
  out[idx] = hi;
  out[loOff + idx] = f2bf(v - bf2f(hi));
}

// ---------------------------------------------------------------------------
// One k-range of a 16-row cell tile: kb in [KB0,KB1), A data from ONE
// contiguous segment (aRow + (kb-KOFF)*32). Depth-4 register pipeline,
// k-steps in PAIRS with ONE raw s_barrier per pair (no vmcnt drain ->
// prefetches stay in flight across barriers). 4-slot LDS A rotation.
// Segment padding guarantees every 2-float A read is in-bounds (pads = 0).
// ---------------------------------------------------------------------------
template <int NTW, bool COH, int KB0, int KB1, int KOFF>
__device__ __forceinline__ void cell_range(
    ushort* __restrict__ Ast,            // 4 slots x {hi[640], lo[640]} ushorts
    const float* __restrict__ aRow,      // this thread's staging-row base
    const ushort* __restrict__ wfq, int nt0, int NT, int loOff,
    float4v (&acc)[NTW]) {
  constexpr int PD = 4;
  constexpr int LEN = KB1 - KB0;
  constexpr int LEN2 = LEN & ~1;
  static_assert(LEN2 % PD == 0 && KB0 % PD == 0, "slot mapping needs x4");
  const int tid  = threadIdx.x;
  const int lane = tid & 63, quad = lane >> 4, l16 = lane & 15;
  const int sm = tid >> 4;               // staging row 0..15
  const int sk = (tid & 15) * 2;         // staging col base (even)

  short8 cbh[PD][NTW], cbl[PD][NTW];
  float2v av[PD];

  auto loadB = [&](int kb, int u) {
#pragma unroll
    for (int w = 0; w < NTW; w++) {
      const size_t fo = ((size_t)(kb * NT + nt0 + w) * 64 + lane) * 8;
      cbh[u][w] = *(const short8*)(wfq + fo);
      cbl[u][w] = *(const short8*)(wfq + loOff + fo);
    }
  };
  auto loadA = [&](int kb) -> float2v {
    const float* p = aRow + (kb - KOFF) * 32 + sk;
    float2v r;
    if (COH) {
      union { unsigned long long u; float f[2]; } x0;
      x0.u = coh_load8(p);
      r[0] = x0.f[0]; r[1] = x0.f[1];
    } else {
      r = *(const float2v*)p;
    }
    return r;
  };
  auto stageSlot = [&](int u, float2v a) {
    ushort h0 = f2bf(a[0]), h1 = f2bf(a[1]);
    ushort l0 = f2bf(a[0] - bf2f(h0)), l1 = f2bf(a[1] - bf2f(h1));
    uint32_t hp = (uint32_t)h0 | ((uint32_t)h1 << 16);
    uint32_t lp = (uint32_t)l0 | ((uint32_t)l1 << 16);
    *(uint32_t*)(Ast + u * 1280 + sm * 40 + sk) = hp;
    *(uint32_t*)(Ast + u * 1280 + 640 + sm * 40 + sk) = lp;
  };
  auto mfmaSlot = [&](int u, const short8 (&bh)[NTW], const short8 (&bl)[NTW]) {
    short8 ah = *(const short8*)(Ast + u * 1280 + l16 * 40 + quad * 8);
    short8 al = *(const short8*)(Ast + u * 1280 + 640 + l16 * 40 + quad * 8);
#pragma unroll
    for (int w = 0; w < NTW; w++) {
      acc[w] = __builtin_amdgcn_mfma_f32_16x16x32_bf16(ah, bh[w], acc[w], 0, 0, 0);
      acc[w] = __builtin_amdgcn_mfma_f32_16x16x32_bf16(al, bh[w], acc[w], 0, 0, 0);
      acc[w] = __builtin_amdgcn_mfma_f32_16x16x32_bf16(ah, bl[w], acc[w], 0, 0, 0);
    }
  };

  // prologue: fill all PD slots (loads overlap; first consumed ~latency later)
#pragma unroll
  for (int i = 0; i < PD; i++) { av[i] = loadA(KB0 + i); loadB(KB0 + i, i); }

  for (int kb0 = KB0; kb0 < KB0 + LEN2; kb0 += PD) {
#pragma unroll
    for (int up = 0; up < 2; up++) {
      const int u0 = up * 2, u1 = up * 2 + 1;
      const int kb = kb0 + up * 2;
      stageSlot(u0, av[u0]);
      stageSlot(u1, av[u1]);
      // LDS writes drained, then barrier. NO vmcnt drain: outstanding global
      // prefetches for later slots stay in flight across the barrier.
      asm volatile("s_waitcnt lgkmcnt(0)\n\ts_barrier" ::: "memory");
      mfmaSlot(u0, cbh[u0], cbl[u0]);
      mfmaSlot(u1, cbh[u1], cbl[u1]);
      if (kb + PD < KB1)     { av[u0] = loadA(kb + PD);     loadB(kb + PD,     u0); }
      if (kb + 1 + PD < KB1) { av[u1] = loadA(kb + 1 + PD); loadB(kb + 1 + PD, u1); }
    }
  }
  if (LEN & 1) {             // odd tail: slot 0 (safe: followed by epilogue sync)
    stageSlot(0, av[0]);
    asm volatile("s_waitcnt lgkmcnt(0)\n\ts_barrier" ::: "memory");
    mfmaSlot(0, cbh[0], cbl[0]);
  }
}

// ---------------------------------------------------------------------------
// Cross-wave combine + CfC nonlinearity + coherent h store (8B vectors).
// Pads [NN, NNPAD) are written as ZERO to keep the padded-h zero invariant.
// ---------------------------------------------------------------------------
template <int NTW>
__device__ __forceinline__ void cell_epilogue(
    float* __restrict__ Acc, float4v (&acc)[NTW],
    const float* const* __restrict__ bias4,
    int NN, int NNPAD, float* __restrict__ hout, float* __restrict__ out2,
    int b0, int n0) {
  const int tid = threadIdx.x;
  const int wave = tid >> 6, lane = tid & 63, quad = lane >> 4, l16 = lane & 15;
  __syncthreads();   // all waves done with LDS A slots before Acc reuse
#pragma unroll
  for (int w = 0; w < NTW; w++)
#pragma unroll
    for (int r = 0; r < 4; r++)
      Acc[(wave * 16 + quad * 4 + r) * 50 + w * 16 + l16] = acc[w][r];
  __syncthreads();
  constexpr int CW = 16 * NTW;
  for (int i4 = tid; i4 < 16 * (CW / 4); i4 += 256) {
    const int r = i4 / (CW / 4);
    const int c4 = (i4 % (CW / 4)) * 4;
    const int j0 = n0 + c4;
    if (j0 >= NNPAD) continue;
    float hv[4];
#pragma unroll
    for (int e = 0; e < 4; e++) {
      const int c = c4 + e, j = j0 + e;
      float h = 0.f;
      if (j < NN) {
        float v1 = Acc[(0 * 16 + r) * 50 + c] + bias4[0][j];
        float v2 = Acc[(1 * 16 + r) * 50 + c] + bias4[1][j];
        float va = Acc[(2 * 16 + r) * 50 + c] + bias4[2][j];
        float vb = Acc[(3 * 16 + r) * 50 + c] + bias4[3][j];
        float ff1 = tanhf(v1);
        float ff2 = tanhf(v2);
        float s = 1.f / (1.f + expf(-(va + vb)));
        h = ff1 * (1.f - s) + s * ff2;
      }
      hv[e] = h;
    }
    float* hp = hout + (size_t)(b0 + r) * HS + j0;
    coh_store8(hp, hv[0], hv[1]);
    coh_store8(hp + 2, hv[2], hv[3]);
    if (out2) {
      float4v o; o[0] = hv[0]; o[1] = hv[1]; o[2] = hv[2]; o[3] = hv[3];
      *(float4v*)(out2 + (size_t)(b0 + r) * 16384 + j0) = o;
    }
  }
}

struct PParams {
  const float* x;
  float* h0; float* h1;
  const ushort* wf0[4]; const ushort* wf1[4]; const ushort* wf2[4];
  int loOff0, loOff1, loOff2;
  const float* bias0[4]; const float* bias1[4]; const float* bias2[4];
  float* pred;
  int* bar;
};

// Split barrier (AGENT scope). Arrive: drain own coherent stores -> block
// barrier -> one RELAXED add. Wait: thread0 spins; block barrier releases.
__device__ __forceinline__ void bar_arrive(int* slot) {
  asm volatile("s_waitcnt vmcnt(0)" ::: "memory");
  __syncthreads();
  if (threadIdx.x == 0)
    __hip_atomic_fetch_add(slot, 1, __ATOMIC_RELAXED, __HIP_MEMORY_SCOPE_AGENT);
}
__device__ __forceinline__ void bar_wait(int* slot, int target) {
  if (threadIdx.x == 0) {
    while (__hip_atomic_load(slot, __ATOMIC_RELAXED, __HIP_MEMORY_SCOPE_AGENT) < target)
      __builtin_amdgcn_s_sleep(1);
  }
  __syncthreads();
}

// ---------------------------------------------------------------------------
// Persistent kernel: 32 chains x 16 rows x 12 blocks = 384 blocks at
// 2 blocks/CU (23 KB LDS, launch_bounds(256,2)) -> two independent chains
// per CU interleave, covering each other's barrier/ds/load stalls.
// Co-residency: capacity >= 2/CU (LDS 160/23=6, 2 waves/SIMD at <=256 VGPR),
// 384 <= 512 -> all blocks resident, spin barriers safe.
// XCD remap s=(phys%8)*48+phys/8 puts same-weight-slice blocks on one XCD
// (~1.5 slices/XCD L2). k-axes rotated: synchronized segment consumed first,
// fresh-barrier wait taken mid-phase, hidden behind MFMA.
// ---------------------------------------------------------------------------
__global__ __launch_bounds__(256, 2) void cfc_persistent(PParams p) {
  __shared__ ushort Ast[4 * 1280];        // 4 A slots x {hi,lo} x 16x40
  __shared__ float  Acc[4 * 16 * 50];
  const int phys = blockIdx.x;
  const int s = (phys & 7) * 48 + (phys >> 3);
  const int ntp = s >> 5;                 // 0..11
  const int c   = s & 31;                 // 0..31
  const int b0 = c * ROWS;
  int* cbar = p.bar + c * (T * 3);
  const int wave = threadIdx.x >> 6;
  const int sm = threadIdx.x >> 4;
  const size_t rowoff = (size_t)(b0 + sm);
  const ushort* wq0 = p.wf0[wave];
  const ushort* wq1 = p.wf1[wave];
  const ushort* wq2 = p.wf2[wave];

  for (int t = 0; t < T; t++) {
    float* hr = (t & 1) ? p.h1 : p.h0;
    float* hw = (t & 1) ? p.h0 : p.h1;
    const float* xRow  = p.x + rowoff * (T * 512) + (size_t)t * 512;
    const float* hrRow = hr + rowoff * HS;
    const float* hwRow = hw + rowoff * HS;

    // ---- layer 0: xc = [x(512) | h0_old(544)], all pre-synchronized ----
    float4v acc0[3];
#pragma unroll
    for (int w = 0; w < 3; w++) acc0[w] = float4v{0.f, 0.f, 0.f, 0.f};
    cell_range<3, false, 0, 16, 0 >(Ast, xRow,  wq0, ntp * 3, 36, p.loOff0, acc0);
    cell_range<3, true, 16, 33, 16>(Ast, hrRow, wq0, ntp * 3, 36, p.loOff0, acc0);
    cell_epilogue<3>(Acc, acc0, p.bias0, 538, 544, hw, nullptr, b0, ntp * 48);
    bar_arrive(cbar + t * 3);

    // ---- layer 1: xc = [h1_old(384) | h0_new(544)] ----
    if (t && ntp >= 4) bar_wait(cbar + (t - 1) * 3 + 1, CBLK);  // h1_old ready
    float4v acc1[2];
#pragma unroll
    for (int w = 0; w < 2; w++) acc1[w] = float4v{0.f, 0.f, 0.f, 0.f};
    cell_range<2, true, 0, 12, 0 >(Ast, hrRow + 544, wq1, ntp * 2, 24, p.loOff1, acc1);
    bar_wait(cbar + t * 3, CBLK);                               // h0_new ready
    cell_range<2, true, 12, 29, 12>(Ast, hwRow, wq1, ntp * 2, 24, p.loOff1, acc1);
    cell_epilogue<2>(Acc, acc1, p.bias1, 358, 384, hw + 544, nullptr, b0, ntp * 32);
    bar_arrive(cbar + t * 3 + 1);

    // ---- layer 2 (4 blocks/chain): xc = [h2_old(128) | h1_new(384)] ----
    if (ntp < 4) {
      if (t) bar_wait(cbar + (t - 1) * 3 + 2, 4);               // h2_old ready
      float4v acc2[2];
#pragma unroll
      for (int w = 0; w < 2; w++) acc2[w] = float4v{0.f, 0.f, 0.f, 0.f};
      cell_range<2, true, 0, 4, 0>(Ast, hrRow + 928, wq2, ntp * 2, 8, p.loOff2, acc2);
      bar_wait(cbar + t * 3 + 1, CBLK);                         // h1_new ready
      cell_range<2, true, 4, 16, 4>(Ast, hwRow + 544, wq2, ntp * 2, 8, p.loOff2, acc2);
      cell_epilogue<2>(Acc, acc2, p.bias2, 128, 128, hw + 928,
                       p.pred + (size_t)t * 128, b0, ntp * 32);
      bar_arrive(cbar + t * 3 + 2);
    }
  }
}

// ---------------------------------------------------------------------------
// h layout helpers: scatter packed(1024) -> padded(HS) with zeroed pads,
// gather padded -> packed for the hn output.
// ---------------------------------------------------------------------------
__global__ __launch_bounds__(256) void h_scatter(const float* __restrict__ src,
                                                 float* __restrict__ dst) {
  int idx = blockIdx.x * 256 + threadIdx.x;
  if (idx >= NB * HS) return;
  int b = idx / HS, u = idx % HS;
  int s = -1;
  if (u < 538) s = u;
  else if (u >= 544 && u < 902) s = 538 + (u - 544);
  else if (u >= 928) s = 896 + (u - 928);
  dst[idx] = (s >= 0) ? src[(size_t)b * 1024 + s] : 0.f;
}
__global__ __launch_bounds__(256) void h_gather(const float* __restrict__ src,
                                                float* __restrict__ dst) {
  int idx = blockIdx.x * 256 + threadIdx.x;
  if (idx >= NB * 1024) return;
  int b = idx / 1024, u = idx % 1024;
  int pu = (u < 538) ? u : (u < 896 ? (u - 538) + 544 : (u - 896) + 928);
  dst[idx] = src[(size_t)b * HS + pu];
}

// ---------------------------------------------------------------------------
// Final linear, IN PLACE on io (f32 d_out predictions region).
// ---------------------------------------------------------------------------
__global__ __launch_bounds__(256)
void final_linear(float* __restrict__ io, const ushort* __restrict__ wfc_frag,
                  int loOff, const float* __restrict__ bfc) {
  __shared__ ushort Ah[64][136];
  __shared__ ushort Al[64][136];
  const int tid = threadIdx.x;
  const int wave = tid >> 6, lane = tid & 63, quad = lane >> 4, l16 = lane & 15;
  const size_t r0 = (size_t)blockIdx.x * 64;
  {
    const int row = tid >> 2;
    const int cb  = (tid & 3) * 32;
    const float* src = io + (r0 + row) * 128 + cb;
#pragma unroll
    for (int e = 0; e < 32; e++) {
      float v = src[e];
      ushort hi = f2bf(v);
      Ah[row][cb + e] = hi;
      Al[row][cb + e] = f2bf(v - bf2f(hi));
    }
  }
  __syncthreads();
  float4v acc[8];
#pragma unroll
  for (int i = 0; i < 8; i++) acc[i] = float4v{0.f, 0.f, 0.f, 0.f};
#pragma unroll
  for (int kb = 0; kb < 4; kb++) {
    short8 ah = *(const short8*)&Ah[wave * 16 + l16][kb * 32 + quad * 8];
    short8 al = *(const short8*)&Al[wave * 16 + l16][kb * 32 + quad * 8];
#pragma unroll
    for (int nt = 0; nt < 8; nt++) {
      const size_t fo = ((size_t)(kb * 8 + nt) * 64 + lane) * 8;
      short8 bh = *(const short8*)(wfc_frag + fo);
      short8 bl = *(const short8*)(wfc_frag + loOff + fo);
      acc[nt] = __builtin_amdgcn_mfma_f32_16x16x32_bf16(ah, bh, acc[nt], 0, 0, 0);
      acc[nt] = __builtin_amdgcn_mfma_f32_16x16x32_bf16(al, bh, acc[nt], 0, 0, 0);
      acc[nt] = __builtin_amdgcn_mfma_f32_16x16x32_bf16(ah, bl, acc[nt], 0, 0, 0);
    }
  }
  __syncthreads();
#pragma unroll
  for (int nt = 0; nt < 8; nt++) {
    int col = nt * 16 + l16;
    float bb = bfc[col];
#pragma unroll
    for (int r = 0; r < 4; r++) {
      int row = wave * 16 + quad * 4 + r;
      io[(r0 + row) * 128 + col] = acc[nt][r] + bb;
    }
  }
}

// ---------------------------------------------------------------------------
extern "C" void kernel_launch(void* const* d_in, const int* in_sizes, int n_in,
                              void* d_out, int out_size, void* d_ws, size_t ws_size,
                              hipStream_t stream) {
  const int maskIdx[3] = {2, 11, 20};
  const int wIdx[3]    = {3, 12, 21};
  const float* Wfc = (const float*)d_in[29];
  const float* bfc = (const float*)d_in[30];

  const int KBs[3]  = {33, 29, 16};   // L1: 384(old,padded) + 538(new) -> 29 kb
  const int NTs[3]  = {36, 24, 8};    // L0 padded 34->36 for 12-block jobs
  const int NNs[3]  = {538, 358, 128};
  const int ITs[3]  = {1050, 896, 486};
  const int POLDs[3]   = {0, 384, 128};
  const int OLDLENs[3] = {0, 358, 128};
  const int SOFFs[3]   = {0, 538, 358};
  const int NEWLENs[3] = {1050, 538, 358};

  ushort* ws = (ushort*)d_ws;
  size_t off = 0;
  ushort* wf[3][4];
  int loOff[3];
  for (int l = 0; l < 3; l++) {
    loOff[l] = KBs[l] * NTs[l] * 512;
    for (int q = 0; q < 4; q++) {
      wf[l][q] = ws + off;
      off += (size_t)2 * loOff[l];
    }
  }
  int wfcLo = 4 * 8 * 512;
  ushort* wfc_f = ws + off; off += (size_t)2 * wfcLo;
  float* hb0 = (float*)(ws + off); off += (size_t)NB * HS * 2;
  float* hb1 = (float*)(ws + off); off += (size_t)NB * HS * 2;
  int* bar = (int*)(ws + off); off += (size_t)NCH * T * 3 * 2;

  float* pred = (float*)d_out;
  float* hn   = (float*)d_out + (size_t)NB * T * 128;

  for (int l = 0; l < 3; l++) {
    int blocks = (loOff[l] + 255) / 256;
    for (int q = 0; q < 4; q++) {
      const float* m = (q < 2) ? (const float*)d_in[maskIdx[l]] : nullptr;
      pack_w<<<blocks, 256, 0, stream>>>((const float*)d_in[wIdx[l] + q], m, wf[l][q],
                                         loOff[l], NNs[l], ITs[l], NTs[l], KBs[l],
                                         POLDs[l], OLDLENs[l], SOFFs[l], NEWLENs[l]);
    }
  }
  pack_w<<<(wfcLo + 255) / 256, 256, 0, stream>>>(Wfc, nullptr, wfc_f, wfcLo,
                                                  128, 128, 8, 4, 0, 0, 0, 128);

  hipMemsetAsync(bar, 0, NCH * T * 3 * sizeof(int), stream);
  h_scatter<<<(NB * HS + 255) / 256, 256, 0, stream>>>((const float*)d_in[1], hb0);

  PParams p;
  p.x = (const float*)d_in[0];
  p.h0 = hb0; p.h1 = hb1;
  for (int q = 0; q < 4; q++) {
    p.wf0[q] = wf[0][q]; p.wf1[q] = wf[1][q]; p.wf2[q] = wf[2][q];
    p.bias0[q] = (const float*)d_in[7 + q];
    p.bias1[q] = (const float*)d_in[16 + q];
    p.bias2[q] = (const float*)d_in[25 + q];
  }
  p.loOff0 = loOff[0]; p.loOff1 = loOff[1]; p.loOff2 = loOff[2];
  p.pred = pred;
  p.bar = bar;

  cfc_persistent<<<NCH * CBLK, 256, 0, stream>>>(p);

  final_linear<<<(NB * T) / 64, 256, 0, stream>>>(pred, wfc_f, wfcLo, bfc);
  // t=127 (odd) wrote into hb0 -> final state lives there.
  h_gather<<<(NB * 1024 + 255) / 256, 256, 0, stream>>>(hb0, hn);
}